// Round 1
// baseline (10.392 us; speedup 1.0000x reference)
//
#include <hip/hip_runtime.h>
#include <hip/hip_bf16.h>

// Reference math: out = zeros(N_NODES, N_HYPER) @ Line_output + 0.0 * sigmoid(...).sum()
//               = exact zeros [20000, 128] (sigmoid sum is finite, 0.0 * finite == 0.0).
// So the entire kernel reduces to writing 2.56M float32 zeros to d_out each call.

__global__ void CrossLevel_zero_fill(float4* __restrict__ out4, int n4,
                                     float* __restrict__ out_tail, int tail_start, int n) {
    int idx = blockIdx.x * blockDim.x + threadIdx.x;
    int stride = gridDim.x * blockDim.x;
    const float4 z = make_float4(0.f, 0.f, 0.f, 0.f);
    for (int i = idx; i < n4; i += stride) {
        out4[i] = z;
    }
    // scalar tail (out_size % 4 != 0 safety; no-op for 2,560,000)
    for (int i = tail_start + idx; i < n; i += stride) {
        out_tail[i] = 0.f;
    }
}

extern "C" void kernel_launch(void* const* d_in, const int* in_sizes, int n_in,
                              void* d_out, int out_size, void* d_ws, size_t ws_size,
                              hipStream_t stream) {
    (void)d_in; (void)in_sizes; (void)n_in; (void)d_ws; (void)ws_size;
    float* out = (float*)d_out;
    int n = out_size;          // 20000 * 128 = 2,560,000 floats
    int n4 = n / 4;            // 640,000 float4 stores
    int tail_start = n4 * 4;

    const int block = 256;
    int grid = (n4 + block - 1) / block;
    if (grid > 2048) grid = 2048;   // grid-stride the rest (G11)
    if (grid < 1) grid = 1;

    CrossLevel_zero_fill<<<grid, block, 0, stream>>>(
        (float4*)out, n4, out, tail_start, n);
}